// Round 4
// baseline (457.641 us; speedup 1.0000x reference)
//
#include <hip/hip_runtime.h>
#include <stdint.h>

typedef unsigned short u16;
typedef __bf16 bf16x8 __attribute__((ext_vector_type(8)));
typedef float f32x4 __attribute__((ext_vector_type(4)));

__device__ __forceinline__ float b2f(u16 u) {
    unsigned x = ((unsigned)u) << 16;
    return __builtin_bit_cast(float, x);
}
__device__ __forceinline__ u16 f2b(float f) {
    unsigned x = __builtin_bit_cast(unsigned, f);
    x = x + 0x7fffu + ((x >> 16) & 1u);
    return (u16)(x >> 16);
}
__device__ __forceinline__ float leaky(float v) { return v > 0.f ? v : 0.2f * v; }

__device__ __forceinline__ void gload16(const u16* g, u16* l) {
    __builtin_amdgcn_global_load_lds((const __attribute__((address_space(1))) void*)(const void*)g,
                                     (__attribute__((address_space(3))) void*)(void*)l, 16, 0, 0);
}

// ---------------- casts ----------------
__global__ void k_cast4(const float* __restrict__ in, u16* __restrict__ out, size_t n4) {
    size_t i = blockIdx.x * (size_t)blockDim.x + threadIdx.x;
    size_t stride = (size_t)gridDim.x * blockDim.x;
    for (; i < n4; i += stride) {
        float4 v = ((const float4*)in)[i];
        ushort4 o;
        o.x = f2b(v.x); o.y = f2b(v.y); o.z = f2b(v.z); o.w = f2b(v.w);
        ((ushort4*)out)[i] = o;
    }
}

// out[c][r] = bf16(in[r][c]); in is R x C (f32)
__global__ void k_tcast(const float* __restrict__ in, u16* __restrict__ out, int R, int C) {
    __shared__ float tile[32][33];
    int tx = threadIdx.x & 31, ty = threadIdx.x >> 5; // 32 x 8
    int c0 = blockIdx.x * 32, r0 = blockIdx.y * 32;
    #pragma unroll
    for (int i = 0; i < 32; i += 8) {
        int r = r0 + ty + i, c = c0 + tx;
        tile[ty + i][tx] = (r < R && c < C) ? in[(size_t)r * C + c] : 0.f;
    }
    __syncthreads();
    #pragma unroll
    for (int i = 0; i < 32; i += 8) {
        int c = c0 + ty + i, r = r0 + tx;
        if (c < C && r < R) out[(size_t)c * R + r] = f2b(tile[tx][ty + i]);
    }
}

// ---------------- GEMM (m97 structure) + fused attention-dot epilogue ----------------
// C[M,NN] = A[M,K] * Bt[NN,K]^T ; A rows must be padded to 128 multiple (staged unguarded).
// If attS != null: per block (one 128-col head slice), computes
//   asrc[row*HEADS+head] = sum_col C_f32 * attS[head*128+col], same for adst.
#define GBM 128
#define GBN 128
#define GBK 64

__global__ __launch_bounds__(256) void k_gemm(const u16* __restrict__ A, const u16* __restrict__ Bt,
                                              u16* __restrict__ C, int M, int NN, int K,
                                              const float* __restrict__ attS, const float* __restrict__ attD,
                                              float* __restrict__ asrc, float* __restrict__ adst, int HEADS) {
    __shared__ __align__(16) u16 As[GBM][GBK];
    __shared__ __align__(16) u16 Bs[GBN][GBK];
    __shared__ float redS[4][64];
    __shared__ float redD[4][64];
    int brow = blockIdx.x * GBM, bcol = blockIdx.y * GBN;
    int t = threadIdx.x, lane = t & 63, wid = t >> 6;
    int wm = (wid >> 1) * 64, wn = (wid & 1) * 64;
    int fr = lane & 15, fq = lane >> 4;
    f32x4 acc[4][4] = {};
    int srow = lane >> 3;         // 0..7
    int scol = (lane & 7) * 8;    // u16 col within 64
    int nK = K / GBK;
    for (int kt = 0; kt < nK; ++kt) {
        int k0 = kt * GBK;
        #pragma unroll
        for (int cc = 0; cc < 8; ++cc) {
            int c = wid * 8 + cc;            // 0..31: 0-15 A-chunks, 16-31 B-chunks
            int r = (c & 15) * 8 + srow;
            if (c < 16) gload16(A + (size_t)(brow + r) * K + k0 + scol, &As[r][scol]);
            else        gload16(Bt + (size_t)(bcol + r) * K + k0 + scol, &Bs[r][scol]);
        }
        __syncthreads();
        #pragma unroll
        for (int kk = 0; kk < 2; ++kk) {
            int ko = kk * 32 + fq * 8;
            bf16x8 af[4], bg[4];
            #pragma unroll
            for (int i = 0; i < 4; ++i) {
                af[i] = *reinterpret_cast<const bf16x8*>(&As[wm + i * 16 + fr][ko]);
                bg[i] = *reinterpret_cast<const bf16x8*>(&Bs[wn + i * 16 + fr][ko]);
            }
            #pragma unroll
            for (int mi = 0; mi < 4; ++mi)
                #pragma unroll
                for (int ni = 0; ni < 4; ++ni)
                    acc[mi][ni] = __builtin_amdgcn_mfma_f32_16x16x32_bf16(af[mi], bg[ni], acc[mi][ni], 0, 0, 0);
        }
        __syncthreads();
    }
    // C write
    #pragma unroll
    for (int mi = 0; mi < 4; ++mi) {
        #pragma unroll
        for (int j = 0; j < 4; ++j) {
            int row = brow + wm + mi * 16 + fq * 4 + j;
            if (row < M) {
                #pragma unroll
                for (int ni = 0; ni < 4; ++ni) {
                    int col = bcol + wn + ni * 16 + fr;
                    C[(size_t)row * NN + col] = f2b(acc[mi][ni][j]);
                }
            }
        }
    }
    // fused attention dots
    if (attS != nullptr) {
        int head = blockIdx.y;
        const float* sv = attS + head * 128;
        const float* dv = attD + head * 128;
        float ps[4][4], pd[4][4];
        #pragma unroll
        for (int mi = 0; mi < 4; ++mi)
            #pragma unroll
            for (int j = 0; j < 4; ++j) {
                float s = 0.f, d = 0.f;
                #pragma unroll
                for (int ni = 0; ni < 4; ++ni) {
                    int lc = wn + ni * 16 + fr;
                    s += acc[mi][ni][j] * sv[lc];
                    d += acc[mi][ni][j] * dv[lc];
                }
                ps[mi][j] = s; pd[mi][j] = d;
            }
        #pragma unroll
        for (int mask = 1; mask < 16; mask <<= 1)
            #pragma unroll
            for (int mi = 0; mi < 4; ++mi)
                #pragma unroll
                for (int j = 0; j < 4; ++j) {
                    ps[mi][j] += __shfl_xor(ps[mi][j], mask);
                    pd[mi][j] += __shfl_xor(pd[mi][j], mask);
                }
        if (fr == 0) {
            #pragma unroll
            for (int mi = 0; mi < 4; ++mi)
                #pragma unroll
                for (int j = 0; j < 4; ++j) {
                    redS[wid][mi * 16 + fq * 4 + j] = ps[mi][j];
                    redD[wid][mi * 16 + fq * 4 + j] = pd[mi][j];
                }
        }
        __syncthreads();
        if ((wid & 1) == 0) {
            int row = brow + wm + lane;
            if (row < M) {
                asrc[(size_t)row * HEADS + head] = redS[wid][lane] + redS[wid | 1][lane];
                adst[(size_t)row * HEADS + head] = redD[wid][lane] + redD[wid | 1][lane];
            }
        }
    }
}

// ---------------- CSR build ----------------
__global__ void k_detect(const int* __restrict__ ei, int* flag, int E0) {
    if (threadIdx.x == 0) *flag = 0;
    __syncthreads();
    int lim = E0 < 4096 ? E0 : 4096;
    int any = 0;
    for (int i = threadIdx.x; i < lim; i += 256) any |= (ei[2 * i + 1] != 0);
    if (any) atomicOr(flag, 1);
}

__global__ void k_deg(const int* __restrict__ ei, const int* __restrict__ flag,
                      int* __restrict__ deg, int E0, int E) {
    bool i64 = (*flag == 0);
    for (int e = blockIdx.x * blockDim.x + threadIdx.x; e < E; e += gridDim.x * blockDim.x) {
        int d;
        if (e < E0) d = i64 ? ei[2 * (E0 + e)] : ei[E0 + e];
        else d = e - E0;
        atomicAdd(&deg[d], 1);
    }
}

__global__ __launch_bounds__(1024) void k_scan(const int* __restrict__ deg, int* __restrict__ off,
                                               int* __restrict__ cursor, int n) {
    __shared__ int part[1024];
    int t = threadIdx.x;
    int chunk = (n + 1023) >> 10;
    int beg = t * chunk, end = beg + chunk;
    if (end > n) end = n;
    int s = 0;
    for (int i = beg; i < end; ++i) s += deg[i];
    part[t] = s;
    __syncthreads();
    for (int d = 1; d < 1024; d <<= 1) {
        int v = (t >= d) ? part[t - d] : 0;
        __syncthreads();
        part[t] += v;
        __syncthreads();
    }
    int run = (t == 0) ? 0 : part[t - 1];
    for (int i = beg; i < end; ++i) { off[i] = run; cursor[i] = run; run += deg[i]; }
    if (t == 1023) off[n] = part[1023];
}

__global__ void k_scatter(const int* __restrict__ ei, const int* __restrict__ flag,
                          int* __restrict__ cursor, int* __restrict__ csr, int E0, int E) {
    bool i64 = (*flag == 0);
    for (int e = blockIdx.x * blockDim.x + threadIdx.x; e < E; e += gridDim.x * blockDim.x) {
        int s, d;
        if (e < E0) {
            if (i64) { s = ei[2 * e]; d = ei[2 * (E0 + e)]; }
            else     { s = ei[e];     d = ei[E0 + e]; }
        } else { s = d = e - E0; }
        int pos = atomicAdd(&cursor[d], 1);
        csr[pos] = s;
    }
}

// ---------------- aggregation with fused softmax stats ----------------
// layer1: 8 heads x 128 ch; block(256) per node; stats computed redundantly per thread.
__global__ __launch_bounds__(256) void k_agg1(const int* __restrict__ off, const int* __restrict__ csr,
                                              const float* __restrict__ asrc, const float* __restrict__ adst,
                                              const u16* __restrict__ h1, u16* __restrict__ outg, int N) {
    int node = blockIdx.x;
    if (node >= N) return;
    int t = threadIdx.x;
    int hh = t >> 5;
    int c0 = t * 4;
    float ad = adst[(size_t)node * 8 + hh];
    int lo = off[node], hi = off[node + 1];
    // pass 0: online max/sum
    float m = -1e30f, ssum = 0.f;
    for (int i = lo; i < hi; ++i) {
        int s = csr[i];
        float v = leaky(asrc[(size_t)s * 8 + hh] + ad);
        float nm = fmaxf(m, v);
        ssum = ssum * __expf(m - nm) + __expf(v - nm);
        m = nm;
    }
    float inv = 1.f / (ssum + 1e-16f);
    // pass 1: weighted gather
    float a0 = 0.f, a1 = 0.f, a2 = 0.f, a3 = 0.f;
    for (int i = lo; i < hi; ++i) {
        int s = csr[i];
        float v = leaky(asrc[(size_t)s * 8 + hh] + ad);
        float alpha = __expf(v - m) * inv;
        ushort4 u = *(const ushort4*)(h1 + (size_t)s * 1024 + c0);
        a0 += alpha * b2f(u.x); a1 += alpha * b2f(u.y);
        a2 += alpha * b2f(u.z); a3 += alpha * b2f(u.w);
    }
    ushort4 o;
    o.x = f2b(a0); o.y = f2b(a1); o.z = f2b(a2); o.w = f2b(a3);
    *(ushort4*)(outg + (size_t)node * 1024 + c0) = o;
}

// layer2: 1 head x 128 ch; 2 nodes per block
__global__ __launch_bounds__(256) void k_agg2(const int* __restrict__ off, const int* __restrict__ csr,
                                              const float* __restrict__ asrc, const float* __restrict__ adst,
                                              const u16* __restrict__ h2, u16* __restrict__ outg, int N) {
    int t = threadIdx.x;
    int half = t >> 7, c = t & 127;
    int node = blockIdx.x * 2 + half;
    if (node >= N) return;
    float ad = adst[node];
    int lo = off[node], hi = off[node + 1];
    float m = -1e30f, ssum = 0.f;
    for (int i = lo; i < hi; ++i) {
        int s = csr[i];
        float v = leaky(asrc[s] + ad);
        float nm = fmaxf(m, v);
        ssum = ssum * __expf(m - nm) + __expf(v - nm);
        m = nm;
    }
    float inv = 1.f / (ssum + 1e-16f);
    float acc = 0.f;
    for (int i = lo; i < hi; ++i) {
        int s = csr[i];
        float v = leaky(asrc[s] + ad);
        float alpha = __expf(v - m) * inv;
        acc += alpha * b2f(h2[(size_t)s * 128 + c]);
    }
    outg[(size_t)node * 128 + c] = f2b(acc);
}

// ---------------- batchnorm: two-stage reduction ----------------
template <int CH>
__global__ __launch_bounds__(256) void k_bnpart(const u16* __restrict__ g, float* __restrict__ ps,
                                                float* __restrict__ ps2, int Nrows, int rowsPerChunk) {
    const int TPR = CH / 4;
    const int RPI = 256 / TPR;
    int t = threadIdx.x;
    int rl = t / TPR, c4 = (t % TPR) * 4;
    int chunk = blockIdx.x;
    int r0 = chunk * rowsPerChunk;
    int r1 = r0 + rowsPerChunk; if (r1 > Nrows) r1 = Nrows;
    float s[4] = {0.f, 0.f, 0.f, 0.f}, s2[4] = {0.f, 0.f, 0.f, 0.f};
    for (int r = r0 + rl; r < r1; r += RPI) {
        ushort4 u = *(const ushort4*)(g + (size_t)r * CH + c4);
        float v0 = b2f(u.x), v1 = b2f(u.y), v2 = b2f(u.z), v3 = b2f(u.w);
        s[0] += v0; s2[0] += v0 * v0;
        s[1] += v1; s2[1] += v1 * v1;
        s[2] += v2; s2[2] += v2 * v2;
        s[3] += v3; s2[3] += v3 * v3;
    }
    size_t prow = (size_t)(chunk * RPI + rl) * CH + c4;
    *(float4*)(ps + prow)  = make_float4(s[0], s[1], s[2], s[3]);
    *(float4*)(ps2 + prow) = make_float4(s2[0], s2[1], s2[2], s2[3]);
}

__global__ __launch_bounds__(256) void k_bnfinal(const float* __restrict__ ps, const float* __restrict__ ps2,
                                                 const float* __restrict__ gamma, const float* __restrict__ beta,
                                                 float* __restrict__ scale, float* __restrict__ shift,
                                                 int P, int CH, int Nrows) {
    int t = threadIdx.x, lane = t & 63, wid = t >> 6;
    int col = blockIdx.x * 4 + wid;
    if (col >= CH) return;
    float s = 0.f, s2 = 0.f;
    for (int p = lane; p < P; p += 64) {
        s += ps[(size_t)p * CH + col];
        s2 += ps2[(size_t)p * CH + col];
    }
    #pragma unroll
    for (int m = 1; m < 64; m <<= 1) { s += __shfl_xor(s, m); s2 += __shfl_xor(s2, m); }
    if (lane == 0) {
        double mu = (double)s / Nrows;
        double var = (double)s2 / Nrows - mu * mu;
        if (var < 0) var = 0;
        float sc = gamma[col] * rsqrtf((float)var + 1e-5f);
        scale[col] = sc;
        shift[col] = beta[col] - (float)mu * sc;
    }
}

__global__ void k_bn_elu(u16* __restrict__ g, const float* __restrict__ scale,
                         const float* __restrict__ shift, size_t total4, int CH) {
    size_t i = blockIdx.x * (size_t)blockDim.x + threadIdx.x;
    size_t stride = (size_t)gridDim.x * blockDim.x;
    for (; i < total4; i += stride) {
        size_t i4 = i * 4;
        int c0 = (int)(i4 % CH);
        ushort4 u = *(ushort4*)(g + i4);
        float v[4] = {b2f(u.x), b2f(u.y), b2f(u.z), b2f(u.w)};
        #pragma unroll
        for (int j = 0; j < 4; ++j) {
            float y = v[j] * scale[c0 + j] + shift[c0 + j];
            v[j] = y > 0.f ? y : expm1f(y);
        }
        ushort4 o;
        o.x = f2b(v[0]); o.y = f2b(v[1]); o.z = f2b(v[2]); o.w = f2b(v[3]);
        *(ushort4*)(g + i4) = o;
    }
}

// ---------------- classifier ----------------
__global__ __launch_bounds__(256) void k_cls(const u16* __restrict__ g2, const float* __restrict__ Wc1,
                                             const float* __restrict__ bc1, const float* __restrict__ Wc2,
                                             const float* __restrict__ bc2, float* __restrict__ out, int N) {
    __shared__ float wl[128 * 64];
    __shared__ float hs[4][128];
    int t = threadIdx.x, lane = t & 63, wid = t >> 6;
    for (int i = t; i < 128 * 64; i += 256) wl[i] = Wc1[i];
    int row = blockIdx.x * 4 + wid;
    if (row < N) {
        const u16* hp = g2 + (size_t)row * 128 + 2 * lane;
        hs[wid][2 * lane] = b2f(hp[0]);
        hs[wid][2 * lane + 1] = b2f(hp[1]);
    }
    __syncthreads();
    if (row >= N) return;
    float tj = bc1[lane];
    #pragma unroll 8
    for (int c = 0; c < 128; ++c) tj += hs[wid][c] * wl[c * 64 + lane];
    tj = tj > 0.f ? tj : expm1f(tj);
    float y0 = tj * Wc2[lane * 2 + 0];
    float y1 = tj * Wc2[lane * 2 + 1];
    #pragma unroll
    for (int m = 1; m < 64; m <<= 1) { y0 += __shfl_xor(y0, m); y1 += __shfl_xor(y1, m); }
    if (lane == 0) {
        out[(size_t)row * 2 + 0] = y0 + bc2[0];
        out[(size_t)row * 2 + 1] = y1 + bc2[1];
    }
}

// ---------------- host launch ----------------
extern "C" void kernel_launch(void* const* d_in, const int* in_sizes, int n_in,
                              void* d_out, int out_size, void* d_ws, size_t ws_size,
                              hipStream_t stream) {
    const float* x     = (const float*)d_in[0];
    const int*   ei    = (const int*)d_in[1];
    const float* W1    = (const float*)d_in[2];
    const float* attS1 = (const float*)d_in[3];
    const float* attD1 = (const float*)d_in[4];
    const float* bn1g  = (const float*)d_in[6];
    const float* bn1b  = (const float*)d_in[7];
    const float* W2    = (const float*)d_in[8];
    const float* attS2 = (const float*)d_in[9];
    const float* attD2 = (const float*)d_in[10];
    const float* bn2g  = (const float*)d_in[12];
    const float* bn2b  = (const float*)d_in[13];
    const float* Wc1   = (const float*)d_in[14];
    const float* bc1   = (const float*)d_in[15];
    const float* Wc2   = (const float*)d_in[16];
    const float* bc2   = (const float*)d_in[17];
    float* out = (float*)d_out;

    const int DIN = 768, F1 = 1024, C2 = 128;
    const int N = in_sizes[0] / DIN;            // 20000
    const int Mp = (N + GBM - 1) / GBM * GBM;   // 20096, padded rows for unguarded staging
    const int E0 = in_sizes[1] / 2;             // 160000
    const int E = E0 + N;

    char* w = (char*)d_ws;
    auto take = [&](size_t bytes) -> void* {
        void* p = (void*)w;
        w += (bytes + 255) & ~(size_t)255;
        return p;
    };
    u16* bufA   = (u16*)take((size_t)Mp * F1 * 2);   // padded: x-cast then agg1 out
    u16* h1b    = (u16*)take((size_t)N * F1 * 2);
    u16* w1t    = (u16*)take((size_t)F1 * DIN * 2);
    u16* w2t    = (u16*)take((size_t)C2 * F1 * 2);
    float* asrc1 = (float*)take((size_t)N * 8 * 4);
    float* adst1 = (float*)take((size_t)N * 8 * 4);
    int* deg    = (int*)take((size_t)N * 4);
    int* off    = (int*)take((size_t)(N + 1) * 4);
    int* cursor = (int*)take((size_t)N * 4);
    int* csr    = (int*)take((size_t)E * 4);
    int* flag   = (int*)take(256);
    u16* h2b    = (u16*)take((size_t)N * C2 * 2);
    float* asrc2 = (float*)take((size_t)N * 4);
    float* adst2 = (float*)take((size_t)N * 4);
    u16* g2     = (u16*)take((size_t)N * C2 * 2);
    float* scale1 = (float*)take(F1 * 4);
    float* shift1 = (float*)take(F1 * 4);
    float* scale2 = (float*)take(C2 * 4);
    float* shift2 = (float*)take(C2 * 4);
    float* psA   = (float*)take((size_t)1024 * 1024 * 4);
    float* psB   = (float*)take((size_t)1024 * 1024 * 4);

    hipMemsetAsync(deg, 0, (size_t)N * 4, stream);
    k_detect<<<1, 256, 0, stream>>>(ei, flag, E0);

    // layer 1 GEMM (+fused att dots): h1 = x @ W1
    k_cast4<<<2048, 256, 0, stream>>>(x, bufA, (size_t)N * DIN / 4);
    k_tcast<<<dim3(F1 / 32, DIN / 32), 256, 0, stream>>>(W1, w1t, DIN, F1);
    k_tcast<<<dim3(C2 / 32, F1 / 32), 256, 0, stream>>>(W2, w2t, F1, C2);
    k_gemm<<<dim3(Mp / GBM, F1 / GBN), 256, 0, stream>>>(bufA, w1t, h1b, N, F1, DIN,
                                                         attS1, attD1, asrc1, adst1, 8);

    // CSR by destination (shared by both layers)
    k_deg<<<512, 256, 0, stream>>>(ei, flag, deg, E0, E);
    k_scan<<<1, 1024, 0, stream>>>(deg, off, cursor, N);
    k_scatter<<<512, 256, 0, stream>>>(ei, flag, cursor, csr, E0, E);

    // layer 1 aggregation (+fused stats) + BN + ELU
    k_agg1<<<N, 256, 0, stream>>>(off, csr, asrc1, adst1, h1b, bufA, N);
    {
        int nchunk = 256, rpc = (N + nchunk - 1) / nchunk;
        k_bnpart<1024><<<nchunk, 256, 0, stream>>>(bufA, psA, psB, N, rpc);
        k_bnfinal<<<F1 / 4, 256, 0, stream>>>(psA, psB, bn1g, bn1b, scale1, shift1, nchunk, F1, N);
    }
    k_bn_elu<<<4096, 256, 0, stream>>>(bufA, scale1, shift1, (size_t)N * F1 / 4, F1);

    // layer 2 GEMM (+fused att dots)
    k_gemm<<<dim3(Mp / GBM, C2 / GBN), 256, 0, stream>>>(bufA, w2t, h2b, N, C2, F1,
                                                         attS2, attD2, asrc2, adst2, 1);
    k_agg2<<<(N + 1) / 2, 256, 0, stream>>>(off, csr, asrc2, adst2, h2b, g2, N);
    {
        int nchunk = 128, rpc = (N + nchunk - 1) / nchunk;
        k_bnpart<128><<<nchunk, 256, 0, stream>>>(g2, psA, psB, N, rpc);
        k_bnfinal<<<C2 / 4, 256, 0, stream>>>(psA, psB, bn2g, bn2b, scale2, shift2, nchunk * 8, C2, N);
    }
    k_bn_elu<<<1024, 256, 0, stream>>>(g2, scale2, shift2, (size_t)N * C2 / 4, C2);

    // classifier head
    k_cls<<<(N + 3) / 4, 256, 0, stream>>>(g2, Wc1, bc1, Wc2, bc2, out, N);
}

// Round 5
// 417.386 us; speedup vs baseline: 1.0964x; 1.0964x over previous
//
#include <hip/hip_runtime.h>
#include <stdint.h>

typedef unsigned short u16;
typedef __bf16 bf16x8 __attribute__((ext_vector_type(8)));
typedef float f32x4 __attribute__((ext_vector_type(4)));

__device__ __forceinline__ float b2f(u16 u) {
    unsigned x = ((unsigned)u) << 16;
    return __builtin_bit_cast(float, x);
}
__device__ __forceinline__ u16 f2b(float f) {
    unsigned x = __builtin_bit_cast(unsigned, f);
    x = x + 0x7fffu + ((x >> 16) & 1u);
    return (u16)(x >> 16);
}
__device__ __forceinline__ float leaky(float v) { return v > 0.f ? v : 0.2f * v; }

__device__ __forceinline__ void gload16(const u16* g, u16* l) {
    __builtin_amdgcn_global_load_lds((const __attribute__((address_space(1))) void*)(const void*)g,
                                     (__attribute__((address_space(3))) void*)(void*)l, 16, 0, 0);
}

// ---------------- casts ----------------
__global__ void k_cast4(const float* __restrict__ in, u16* __restrict__ out, size_t n4) {
    size_t i = blockIdx.x * (size_t)blockDim.x + threadIdx.x;
    size_t stride = (size_t)gridDim.x * blockDim.x;
    for (; i < n4; i += stride) {
        float4 v = ((const float4*)in)[i];
        ushort4 o;
        o.x = f2b(v.x); o.y = f2b(v.y); o.z = f2b(v.z); o.w = f2b(v.w);
        ((ushort4*)out)[i] = o;
    }
}

// out[c][r] = bf16(in[r][c]); in is R x C (f32)
__global__ void k_tcast(const float* __restrict__ in, u16* __restrict__ out, int R, int C) {
    __shared__ float tile[32][33];
    int tx = threadIdx.x & 31, ty = threadIdx.x >> 5; // 32 x 8
    int c0 = blockIdx.x * 32, r0 = blockIdx.y * 32;
    #pragma unroll
    for (int i = 0; i < 32; i += 8) {
        int r = r0 + ty + i, c = c0 + tx;
        tile[ty + i][tx] = (r < R && c < C) ? in[(size_t)r * C + c] : 0.f;
    }
    __syncthreads();
    #pragma unroll
    for (int i = 0; i < 32; i += 8) {
        int c = c0 + ty + i, r = r0 + tx;
        if (c < C && r < R) out[(size_t)c * R + r] = f2b(tile[tx][ty + i]);
    }
}

// ---------------- GEMM (m97 structure) + fused attention-dot epilogue ----------------
#define GBM 128
#define GBN 128
#define GBK 64

__global__ __launch_bounds__(256) void k_gemm(const u16* __restrict__ A, const u16* __restrict__ Bt,
                                              u16* __restrict__ C, int M, int NN, int K,
                                              const float* __restrict__ attS, const float* __restrict__ attD,
                                              float* __restrict__ asrc, float* __restrict__ adst, int HEADS) {
    __shared__ __align__(16) u16 As[GBM][GBK];
    __shared__ __align__(16) u16 Bs[GBN][GBK];
    __shared__ float redS[4][64];
    __shared__ float redD[4][64];
    int brow = blockIdx.x * GBM, bcol = blockIdx.y * GBN;
    int t = threadIdx.x, lane = t & 63, wid = t >> 6;
    int wm = (wid >> 1) * 64, wn = (wid & 1) * 64;
    int fr = lane & 15, fq = lane >> 4;
    f32x4 acc[4][4] = {};
    int srow = lane >> 3;
    int scol = (lane & 7) * 8;
    int nK = K / GBK;
    for (int kt = 0; kt < nK; ++kt) {
        int k0 = kt * GBK;
        #pragma unroll
        for (int cc = 0; cc < 8; ++cc) {
            int c = wid * 8 + cc;
            int r = (c & 15) * 8 + srow;
            if (c < 16) gload16(A + (size_t)(brow + r) * K + k0 + scol, &As[r][scol]);
            else        gload16(Bt + (size_t)(bcol + r) * K + k0 + scol, &Bs[r][scol]);
        }
        __syncthreads();
        #pragma unroll
        for (int kk = 0; kk < 2; ++kk) {
            int ko = kk * 32 + fq * 8;
            bf16x8 af[4], bg[4];
            #pragma unroll
            for (int i = 0; i < 4; ++i) {
                af[i] = *reinterpret_cast<const bf16x8*>(&As[wm + i * 16 + fr][ko]);
                bg[i] = *reinterpret_cast<const bf16x8*>(&Bs[wn + i * 16 + fr][ko]);
            }
            #pragma unroll
            for (int mi = 0; mi < 4; ++mi)
                #pragma unroll
                for (int ni = 0; ni < 4; ++ni)
                    acc[mi][ni] = __builtin_amdgcn_mfma_f32_16x16x32_bf16(af[mi], bg[ni], acc[mi][ni], 0, 0, 0);
        }
        __syncthreads();
    }
    #pragma unroll
    for (int mi = 0; mi < 4; ++mi) {
        #pragma unroll
        for (int j = 0; j < 4; ++j) {
            int row = brow + wm + mi * 16 + fq * 4 + j;
            if (row < M) {
                #pragma unroll
                for (int ni = 0; ni < 4; ++ni) {
                    int col = bcol + wn + ni * 16 + fr;
                    C[(size_t)row * NN + col] = f2b(acc[mi][ni][j]);
                }
            }
        }
    }
    if (attS != nullptr) {
        int head = blockIdx.y;
        const float* sv = attS + head * 128;
        const float* dv = attD + head * 128;
        float ps[4][4], pd[4][4];
        #pragma unroll
        for (int mi = 0; mi < 4; ++mi)
            #pragma unroll
            for (int j = 0; j < 4; ++j) {
                float s = 0.f, d = 0.f;
                #pragma unroll
                for (int ni = 0; ni < 4; ++ni) {
                    int lc = wn + ni * 16 + fr;
                    s += acc[mi][ni][j] * sv[lc];
                    d += acc[mi][ni][j] * dv[lc];
                }
                ps[mi][j] = s; pd[mi][j] = d;
            }
        #pragma unroll
        for (int mask = 1; mask < 16; mask <<= 1)
            #pragma unroll
            for (int mi = 0; mi < 4; ++mi)
                #pragma unroll
                for (int j = 0; j < 4; ++j) {
                    ps[mi][j] += __shfl_xor(ps[mi][j], mask);
                    pd[mi][j] += __shfl_xor(pd[mi][j], mask);
                }
        if (fr == 0) {
            #pragma unroll
            for (int mi = 0; mi < 4; ++mi)
                #pragma unroll
                for (int j = 0; j < 4; ++j) {
                    redS[wid][mi * 16 + fq * 4 + j] = ps[mi][j];
                    redD[wid][mi * 16 + fq * 4 + j] = pd[mi][j];
                }
        }
        __syncthreads();
        if ((wid & 1) == 0) {
            int row = brow + wm + lane;
            if (row < M) {
                asrc[(size_t)row * HEADS + head] = redS[wid][lane] + redS[wid | 1][lane];
                adst[(size_t)row * HEADS + head] = redD[wid][lane] + redD[wid | 1][lane];
            }
        }
    }
}

// ---------------- CSR build ----------------
__global__ void k_detect(const int* __restrict__ ei, int* flag, int E0) {
    if (threadIdx.x == 0) *flag = 0;
    __syncthreads();
    int lim = E0 < 4096 ? E0 : 4096;
    int any = 0;
    for (int i = threadIdx.x; i < lim; i += 256) any |= (ei[2 * i + 1] != 0);
    if (any) atomicOr(flag, 1);
}

__global__ void k_deg(const int* __restrict__ ei, const int* __restrict__ flag,
                      int* __restrict__ deg, int E0, int E) {
    bool i64 = (*flag == 0);
    for (int e = blockIdx.x * blockDim.x + threadIdx.x; e < E; e += gridDim.x * blockDim.x) {
        int d;
        if (e < E0) d = i64 ? ei[2 * (E0 + e)] : ei[E0 + e];
        else d = e - E0;
        atomicAdd(&deg[d], 1);
    }
}

__global__ __launch_bounds__(1024) void k_scan(const int* __restrict__ deg, int* __restrict__ off,
                                               int* __restrict__ cursor, int n) {
    __shared__ int part[1024];
    int t = threadIdx.x;
    int chunk = (n + 1023) >> 10;
    int beg = t * chunk, end = beg + chunk;
    if (end > n) end = n;
    int s = 0;
    for (int i = beg; i < end; ++i) s += deg[i];
    part[t] = s;
    __syncthreads();
    for (int d = 1; d < 1024; d <<= 1) {
        int v = (t >= d) ? part[t - d] : 0;
        __syncthreads();
        part[t] += v;
        __syncthreads();
    }
    int run = (t == 0) ? 0 : part[t - 1];
    for (int i = beg; i < end; ++i) { off[i] = run; cursor[i] = run; run += deg[i]; }
    if (t == 1023) off[n] = part[1023];
}

__global__ void k_scatter(const int* __restrict__ ei, const int* __restrict__ flag,
                          int* __restrict__ cursor, int* __restrict__ csr, int E0, int E) {
    bool i64 = (*flag == 0);
    for (int e = blockIdx.x * blockDim.x + threadIdx.x; e < E; e += gridDim.x * blockDim.x) {
        int s, d;
        if (e < E0) {
            if (i64) { s = ei[2 * e]; d = ei[2 * (E0 + e)]; }
            else     { s = ei[e];     d = ei[E0 + e]; }
        } else { s = d = e - E0; }
        int pos = atomicAdd(&cursor[d], 1);
        csr[pos] = s;
    }
}

// ---------------- edge softmax: unnormalized p + per-node inv ----------------
// one wave per node; lanes = (64/HEADS) edges x HEADS heads
template <int HEADS>
__global__ __launch_bounds__(256) void k_alpha(const int* __restrict__ off, const int* __restrict__ csr,
                                               const float* __restrict__ asrc, const float* __restrict__ adst,
                                               float* __restrict__ pbuf, float* __restrict__ invb, int N) {
    const int EPC = 64 / HEADS;
    int t = threadIdx.x, lane = t & 63, wid = t >> 6;
    int node = blockIdx.x * 4 + wid;
    if (node >= N) return;
    int h = lane & (HEADS - 1);
    int e = lane / HEADS;
    float ad = adst[(size_t)node * HEADS + h];
    int lo = off[node], hi = off[node + 1];
    float m = -1e30f;
    for (int i = lo + e; i < hi; i += EPC) {
        int s = csr[i];
        float v = leaky(asrc[(size_t)s * HEADS + h] + ad);
        m = fmaxf(m, v);
    }
    #pragma unroll
    for (int mask = HEADS; mask < 64; mask <<= 1) m = fmaxf(m, __shfl_xor(m, mask));
    float ssum = 0.f;
    for (int i = lo + e; i < hi; i += EPC) {
        int s = csr[i];
        float v = leaky(asrc[(size_t)s * HEADS + h] + ad);
        float p = __expf(v - m);
        pbuf[(size_t)i * HEADS + h] = p;
        ssum += p;
    }
    #pragma unroll
    for (int mask = HEADS; mask < 64; mask <<= 1) ssum += __shfl_xor(ssum, mask);
    if (lane < HEADS) invb[(size_t)node * HEADS + h] = 1.f / (ssum + 1e-16f);
}

// ---------------- aggregation: pure gather ----------------
// layer1: 8 heads x 128 ch; block(256) per node, 4 ch/thread
__global__ __launch_bounds__(256) void k_agg1(const int* __restrict__ off, const int* __restrict__ csr,
                                              const float* __restrict__ pbuf, const float* __restrict__ invb,
                                              const u16* __restrict__ h1, u16* __restrict__ outg, int N) {
    int node = blockIdx.x;
    if (node >= N) return;
    int t = threadIdx.x;
    int hh = t >> 5;
    int c0 = t * 4;
    int lo = off[node], hi = off[node + 1];
    float a0 = 0.f, a1 = 0.f, a2 = 0.f, a3 = 0.f;
    for (int i = lo; i < hi; ++i) {
        int s = csr[i];
        float p = pbuf[(size_t)i * 8 + hh];
        ushort4 u = *(const ushort4*)(h1 + (size_t)s * 1024 + c0);
        a0 += p * b2f(u.x); a1 += p * b2f(u.y);
        a2 += p * b2f(u.z); a3 += p * b2f(u.w);
    }
    float inv = invb[(size_t)node * 8 + hh];
    ushort4 o;
    o.x = f2b(a0 * inv); o.y = f2b(a1 * inv); o.z = f2b(a2 * inv); o.w = f2b(a3 * inv);
    *(ushort4*)(outg + (size_t)node * 1024 + c0) = o;
}

// layer2: 1 head x 128 ch; 2 nodes per block
__global__ __launch_bounds__(256) void k_agg2(const int* __restrict__ off, const int* __restrict__ csr,
                                              const float* __restrict__ pbuf, const float* __restrict__ invb,
                                              const u16* __restrict__ h2, u16* __restrict__ outg, int N) {
    int t = threadIdx.x;
    int half = t >> 7, c = t & 127;
    int node = blockIdx.x * 2 + half;
    if (node >= N) return;
    int lo = off[node], hi = off[node + 1];
    float acc = 0.f;
    for (int i = lo; i < hi; ++i) {
        int s = csr[i];
        acc += pbuf[i] * b2f(h2[(size_t)s * 128 + c]);
    }
    outg[(size_t)node * 128 + c] = f2b(acc * invb[node]);
}

// ---------------- batchnorm: two-stage reduction ----------------
template <int CH>
__global__ __launch_bounds__(256) void k_bnpart(const u16* __restrict__ g, float* __restrict__ ps,
                                                float* __restrict__ ps2, int Nrows, int rowsPerChunk) {
    const int TPR = CH / 4;
    const int RPI = 256 / TPR;
    int t = threadIdx.x;
    int rl = t / TPR, c4 = (t % TPR) * 4;
    int chunk = blockIdx.x;
    int r0 = chunk * rowsPerChunk;
    int r1 = r0 + rowsPerChunk; if (r1 > Nrows) r1 = Nrows;
    float s[4] = {0.f, 0.f, 0.f, 0.f}, s2[4] = {0.f, 0.f, 0.f, 0.f};
    for (int r = r0 + rl; r < r1; r += RPI) {
        ushort4 u = *(const ushort4*)(g + (size_t)r * CH + c4);
        float v0 = b2f(u.x), v1 = b2f(u.y), v2 = b2f(u.z), v3 = b2f(u.w);
        s[0] += v0; s2[0] += v0 * v0;
        s[1] += v1; s2[1] += v1 * v1;
        s[2] += v2; s2[2] += v2 * v2;
        s[3] += v3; s2[3] += v3 * v3;
    }
    size_t prow = (size_t)(chunk * RPI + rl) * CH + c4;
    *(float4*)(ps + prow)  = make_float4(s[0], s[1], s[2], s[3]);
    *(float4*)(ps2 + prow) = make_float4(s2[0], s2[1], s2[2], s2[3]);
}

__global__ __launch_bounds__(256) void k_bnfinal(const float* __restrict__ ps, const float* __restrict__ ps2,
                                                 const float* __restrict__ gamma, const float* __restrict__ beta,
                                                 float* __restrict__ scale, float* __restrict__ shift,
                                                 int P, int CH, int Nrows) {
    int t = threadIdx.x, lane = t & 63, wid = t >> 6;
    int col = blockIdx.x * 4 + wid;
    if (col >= CH) return;
    float s = 0.f, s2 = 0.f;
    for (int p = lane; p < P; p += 64) {
        s += ps[(size_t)p * CH + col];
        s2 += ps2[(size_t)p * CH + col];
    }
    #pragma unroll
    for (int m = 1; m < 64; m <<= 1) { s += __shfl_xor(s, m); s2 += __shfl_xor(s2, m); }
    if (lane == 0) {
        double mu = (double)s / Nrows;
        double var = (double)s2 / Nrows - mu * mu;
        if (var < 0) var = 0;
        float sc = gamma[col] * rsqrtf((float)var + 1e-5f);
        scale[col] = sc;
        shift[col] = beta[col] - (float)mu * sc;
    }
}

__global__ void k_bn_elu(u16* __restrict__ g, const float* __restrict__ scale,
                         const float* __restrict__ shift, size_t total4, int CH) {
    size_t i = blockIdx.x * (size_t)blockDim.x + threadIdx.x;
    size_t stride = (size_t)gridDim.x * blockDim.x;
    for (; i < total4; i += stride) {
        size_t i4 = i * 4;
        int c0 = (int)(i4 % CH);
        ushort4 u = *(ushort4*)(g + i4);
        float v[4] = {b2f(u.x), b2f(u.y), b2f(u.z), b2f(u.w)};
        #pragma unroll
        for (int j = 0; j < 4; ++j) {
            float y = v[j] * scale[c0 + j] + shift[c0 + j];
            v[j] = y > 0.f ? y : expm1f(y);
        }
        ushort4 o;
        o.x = f2b(v[0]); o.y = f2b(v[1]); o.z = f2b(v[2]); o.w = f2b(v[3]);
        *(ushort4*)(g + i4) = o;
    }
}

// ---------------- classifier (fused BN2+ELU on load, 64 rows/block) ----------------
__global__ __launch_bounds__(256) void k_cls(const u16* __restrict__ g2raw,
                                             const float* __restrict__ scale2, const float* __restrict__ shift2,
                                             const float* __restrict__ Wc1, const float* __restrict__ bc1,
                                             const float* __restrict__ Wc2, const float* __restrict__ bc2,
                                             float* __restrict__ out, int N) {
    __shared__ float wl[128 * 64];
    __shared__ float hs[4][128];
    int t = threadIdx.x, lane = t & 63, wid = t >> 6;
    for (int i = t; i < 128 * 64; i += 256) wl[i] = Wc1[i];
    float sc0 = scale2[2 * lane], sc1 = scale2[2 * lane + 1];
    float sh0 = shift2[2 * lane], sh1 = shift2[2 * lane + 1];
    float bb = bc1[lane];
    float c2a = Wc2[lane * 2], c2b = Wc2[lane * 2 + 1];
    float o2a = bc2[0], o2b = bc2[1];
    __syncthreads();
    int row0 = blockIdx.x * 64;
    for (int it = 0; it < 16; ++it) {
        int row = row0 + it * 4 + wid;
        if (row >= N) continue;
        const u16* hp = g2raw + (size_t)row * 128 + 2 * lane;
        float y0 = b2f(hp[0]) * sc0 + sh0; y0 = y0 > 0.f ? y0 : expm1f(y0);
        float y1 = b2f(hp[1]) * sc1 + sh1; y1 = y1 > 0.f ? y1 : expm1f(y1);
        hs[wid][2 * lane] = y0;
        hs[wid][2 * lane + 1] = y1;
        float tj = bb;
        #pragma unroll 8
        for (int c = 0; c < 128; ++c) tj += hs[wid][c] * wl[c * 64 + lane];
        tj = tj > 0.f ? tj : expm1f(tj);
        float v0 = tj * c2a, v1 = tj * c2b;
        #pragma unroll
        for (int m = 1; m < 64; m <<= 1) { v0 += __shfl_xor(v0, m); v1 += __shfl_xor(v1, m); }
        if (lane == 0) {
            out[(size_t)row * 2 + 0] = v0 + o2a;
            out[(size_t)row * 2 + 1] = v1 + o2b;
        }
    }
}

// ---------------- host launch ----------------
extern "C" void kernel_launch(void* const* d_in, const int* in_sizes, int n_in,
                              void* d_out, int out_size, void* d_ws, size_t ws_size,
                              hipStream_t stream) {
    const float* x     = (const float*)d_in[0];
    const int*   ei    = (const int*)d_in[1];
    const float* W1    = (const float*)d_in[2];
    const float* attS1 = (const float*)d_in[3];
    const float* attD1 = (const float*)d_in[4];
    const float* bn1g  = (const float*)d_in[6];
    const float* bn1b  = (const float*)d_in[7];
    const float* W2    = (const float*)d_in[8];
    const float* attS2 = (const float*)d_in[9];
    const float* attD2 = (const float*)d_in[10];
    const float* bn2g  = (const float*)d_in[12];
    const float* bn2b  = (const float*)d_in[13];
    const float* Wc1   = (const float*)d_in[14];
    const float* bc1   = (const float*)d_in[15];
    const float* Wc2   = (const float*)d_in[16];
    const float* bc2   = (const float*)d_in[17];
    float* out = (float*)d_out;

    const int DIN = 768, F1 = 1024, C2 = 128;
    const int N = in_sizes[0] / DIN;            // 20000
    const int Mp = (N + GBM - 1) / GBM * GBM;   // 20096
    const int E0 = in_sizes[1] / 2;             // 160000
    const int E = E0 + N;

    char* w = (char*)d_ws;
    auto take = [&](size_t bytes) -> void* {
        void* p = (void*)w;
        w += (bytes + 255) & ~(size_t)255;
        return p;
    };
    u16* bufA   = (u16*)take((size_t)Mp * F1 * 2);
    u16* h1b    = (u16*)take((size_t)N * F1 * 2);
    u16* w1t    = (u16*)take((size_t)F1 * DIN * 2);
    u16* w2t    = (u16*)take((size_t)C2 * F1 * 2);
    float* asrc1 = (float*)take((size_t)N * 8 * 4);
    float* adst1 = (float*)take((size_t)N * 8 * 4);
    int* deg    = (int*)take((size_t)N * 4);
    int* off    = (int*)take((size_t)(N + 1) * 4);
    int* cursor = (int*)take((size_t)N * 4);
    int* csr    = (int*)take((size_t)E * 4);
    int* flag   = (int*)take(256);
    u16* h2b    = (u16*)take((size_t)N * C2 * 2);
    float* asrc2 = (float*)take((size_t)N * 4);
    float* adst2 = (float*)take((size_t)N * 4);
    u16* g2     = (u16*)take((size_t)N * C2 * 2);
    float* scale1 = (float*)take(F1 * 4);
    float* shift1 = (float*)take(F1 * 4);
    float* scale2 = (float*)take(C2 * 4);
    float* shift2 = (float*)take(C2 * 4);
    float* pbuf  = (float*)take((size_t)E * 8 * 4);   // reused by layer 2 (E floats)
    float* invb1 = (float*)take((size_t)N * 8 * 4);
    float* invb2 = (float*)take((size_t)N * 4);
    float* psA   = (float*)take((size_t)1024 * 1024 * 4);
    float* psB   = (float*)take((size_t)1024 * 1024 * 4);

    hipMemsetAsync(deg, 0, (size_t)N * 4, stream);
    k_detect<<<1, 256, 0, stream>>>(ei, flag, E0);

    // layer 1 GEMM (+fused att dots)
    k_cast4<<<2048, 256, 0, stream>>>(x, bufA, (size_t)N * DIN / 4);
    k_tcast<<<dim3(F1 / 32, DIN / 32), 256, 0, stream>>>(W1, w1t, DIN, F1);
    k_tcast<<<dim3(C2 / 32, F1 / 32), 256, 0, stream>>>(W2, w2t, F1, C2);
    k_gemm<<<dim3(Mp / GBM, F1 / GBN), 256, 0, stream>>>(bufA, w1t, h1b, N, F1, DIN,
                                                         attS1, attD1, asrc1, adst1, 8);

    // CSR by destination
    k_deg<<<512, 256, 0, stream>>>(ei, flag, deg, E0, E);
    k_scan<<<1, 1024, 0, stream>>>(deg, off, cursor, N);
    k_scatter<<<512, 256, 0, stream>>>(ei, flag, cursor, csr, E0, E);

    // layer 1: edge softmax -> gather -> BN -> ELU
    k_alpha<8><<<(N + 3) / 4, 256, 0, stream>>>(off, csr, asrc1, adst1, pbuf, invb1, N);
    k_agg1<<<N, 256, 0, stream>>>(off, csr, pbuf, invb1, h1b, bufA, N);
    {
        int nchunk = 256, rpc = (N + nchunk - 1) / nchunk;
        k_bnpart<1024><<<nchunk, 256, 0, stream>>>(bufA, psA, psB, N, rpc);
        k_bnfinal<<<F1 / 4, 256, 0, stream>>>(psA, psB, bn1g, bn1b, scale1, shift1, nchunk, F1, N);
    }
    k_bn_elu<<<4096, 256, 0, stream>>>(bufA, scale1, shift1, (size_t)N * F1 / 4, F1);

    // layer 2 GEMM (+fused att dots)
    k_gemm<<<dim3(Mp / GBM, C2 / GBN), 256, 0, stream>>>(bufA, w2t, h2b, N, C2, F1,
                                                         attS2, attD2, asrc2, adst2, 1);
    k_alpha<1><<<(N + 3) / 4, 256, 0, stream>>>(off, csr, asrc2, adst2, pbuf, invb2, N);
    k_agg2<<<(N + 1) / 2, 256, 0, stream>>>(off, csr, pbuf, invb2, h2b, g2, N);
    {
        int nchunk = 128, rpc = (N + nchunk - 1) / nchunk;
        k_bnpart<128><<<nchunk, 256, 0, stream>>>(g2, psA, psB, N, rpc);
        k_bnfinal<<<C2 / 4, 256, 0, stream>>>(psA, psB, bn2g, bn2b, scale2, shift2, nchunk * 8, C2, N);
    }

    // classifier head (fused BN2+ELU)
    k_cls<<<(N + 63) / 64, 256, 0, stream>>>(g2, scale2, shift2, Wc1, bc1, Wc2, bc2, out, N);
}